// Round 1
// baseline (630.915 us; speedup 1.0000x reference)
//
#include <hip/hip_runtime.h>
#include <hip/hip_bf16.h>
#include <math.h>

// Problem constants (from reference)
#define DIMK   1024
#define HDIM   4096
#define NEXP   8
#define NTOK   4096
#define EPSV   1e-6f

typedef __attribute__((ext_vector_type(4))) float  f32x4;
typedef __attribute__((ext_vector_type(8))) __bf16 bf16x8;
typedef __attribute__((ext_vector_type(4))) __bf16 bf16x4;

__device__ __forceinline__ __bf16 f2bf(float f) { return (__bf16)f; }

// ---------------------------------------------------------------------------
// 0. init: zero the small counters region of ws
// ---------------------------------------------------------------------------
__global__ void init_kernel(int* counts, int* cursors, float* S) {
    int t = threadIdx.x;
    if (t < NEXP) { counts[t] = 0; cursors[t] = 0; S[t] = 0.0f; }
}

// ---------------------------------------------------------------------------
// 1. gate: one wave per token. logits = x@w_gate + b_gate, softmax, top-1.
// ---------------------------------------------------------------------------
__global__ __launch_bounds__(256) void gate_kernel(
    const float* __restrict__ x, const float* __restrict__ wg,
    const float* __restrict__ bg,
    float* S, int* counts, float* score_top, int* texp)
{
    int wave = threadIdx.x >> 6;
    int lane = threadIdx.x & 63;
    int n = blockIdx.x * 4 + wave;
    const float* xr = x + (size_t)n * DIMK;

    float acc[NEXP];
#pragma unroll
    for (int e = 0; e < NEXP; e++) acc[e] = 0.0f;

    for (int d = lane; d < DIMK; d += 64) {
        float xv = xr[d];
        const float* wr = wg + (size_t)d * NEXP;
#pragma unroll
        for (int e = 0; e < NEXP; e++) acc[e] += xv * wr[e];
    }
#pragma unroll
    for (int e = 0; e < NEXP; e++) {
#pragma unroll
        for (int off = 32; off > 0; off >>= 1)
            acc[e] += __shfl_down(acc[e], off, 64);
    }
    if (lane == 0) {
        float l[NEXP];
        float m = -1e30f;
#pragma unroll
        for (int e = 0; e < NEXP; e++) { l[e] = acc[e] + bg[e]; m = fmaxf(m, l[e]); }
        float p[NEXP]; float s = 0.0f;
#pragma unroll
        for (int e = 0; e < NEXP; e++) { p[e] = expf(l[e] - m); s += p[e]; }
        // top-1 with lowest-index tie-break (jax.lax.top_k semantics)
        int best = 0; float bv = p[0];
#pragma unroll
        for (int e = 1; e < NEXP; e++) if (p[e] > bv) { bv = p[e]; best = e; }
        float sc = bv / s;                 // softmax score of the winner
        score_top[n] = sc;
        texp[n] = best;
        atomicAdd(&S[best], sc);
        atomicAdd(&counts[best], 1);
    }
}

// ---------------------------------------------------------------------------
// 2. finalize: exclusive-scan offsets, aux loss.
//    load[e] = S_e/(S_e+eps)*NTOK ; importance = sum(load)/NTOK
// ---------------------------------------------------------------------------
__global__ void finalize_kernel(const float* S, const int* counts,
                                int* offsets, float* loss_out)
{
    if (threadIdx.x == 0 && blockIdx.x == 0) {
        int off = 0;
        float loadv[NEXP]; float tot = 0.0f;
        for (int e = 0; e < NEXP; e++) { offsets[e] = off; off += counts[e]; }
        for (int e = 0; e < NEXP; e++) {
            loadv[e] = S[e] / (S[e] + EPSV) * (float)NTOK;
            tot += loadv[e];
        }
        float imp = tot / (float)NTOK;
        float loss = 0.0f;
        for (int e = 0; e < NEXP; e++) { float d = loadv[e] - imp; loss += d * d; }
        loss_out[0] = loss / (float)NEXP;
    }
}

// ---------------------------------------------------------------------------
// 3. assign: compaction permutation + per-token combine weight
// ---------------------------------------------------------------------------
__global__ __launch_bounds__(256) void assign_kernel(
    const int* __restrict__ texp, const float* __restrict__ score_top,
    const float* __restrict__ S, const int* __restrict__ offsets,
    int* cursors, int* perm, float* gatew)
{
    int n = blockIdx.x * 256 + threadIdx.x;
    int e = texp[n];
    int pos = atomicAdd(&cursors[e], 1);
    perm[offsets[e] + pos] = n;
    gatew[n] = score_top[n] / (S[e] + EPSV) * (float)NTOK;
}

// ---------------------------------------------------------------------------
// 4. GEMM1: h[row,:] = fast_gelu(x[perm]·W1[e] + b1[e])  (bf16 out)
//    BM=128 BN=128 BK=32, 4 waves of 64x64 (4x4 mfma_16x16x32_bf16)
// ---------------------------------------------------------------------------
__global__ __launch_bounds__(256) void gemm1_kernel(
    const float* __restrict__ x, const float* __restrict__ w1,
    const float* __restrict__ b1,
    const int* __restrict__ perm, const int* __restrict__ counts,
    const int* __restrict__ offsets, __bf16* __restrict__ hbuf)
{
    int bx  = blockIdx.x;
    int e   = bx >> 10;           // 32 mt * 32 nt
    int rem = bx & 1023;
    int mt  = rem >> 5;
    int nt  = rem & 31;
    int ce  = counts[e];
    int m0  = mt * 128;
    if (m0 >= ce) return;
    int off = offsets[e];
    int n0  = nt * 128;
    const float* B = w1 + (size_t)e * DIMK * HDIM;   // [1024][4096] row-major

    __shared__ __bf16 As[128][40];   // [m][k], +8 pad
    __shared__ __bf16 Bs[128][40];   // [n][k] (transposed), +8 pad

    int t = threadIdx.x;

    // A staging map: row r=(t>>3)+32*i, cols (t&7)*4 .. +3  (fp32 gather via perm)
    const float* aptr[4];
#pragma unroll
    for (int i = 0; i < 4; i++) {
        int r  = (t >> 3) + 32 * i;
        int ri = m0 + r; if (ri >= ce) ri = ce - 1;   // clamp (masked at store)
        aptr[i] = x + (size_t)perm[off + ri] * DIMK;
    }
    int ac4 = (t & 7) * 4;

    // B staging map: column j=t&127, k-groups by g=t>>7
    int bj = t & 127;
    int bgp = t >> 7;
    const float* bcol = B + n0 + bj;

    int lane = t & 63;
    int wv   = t >> 6;
    int wm   = (wv >> 1) * 64;
    int wn   = (wv & 1) * 64;
    int lr   = lane & 15;
    int lq   = lane >> 4;

    f32x4 acc[4][4];
#pragma unroll
    for (int mi = 0; mi < 4; mi++)
#pragma unroll
        for (int ni = 0; ni < 4; ni++) acc[mi][ni] = (f32x4)0.0f;

    for (int k0 = 0; k0 < DIMK; k0 += 32) {
        // stage A (fp32 -> bf16)
#pragma unroll
        for (int i = 0; i < 4; i++) {
            int r = (t >> 3) + 32 * i;
            f32x4 v = *(const f32x4*)(aptr[i] + k0 + ac4);
            bf16x4 s4 = { f2bf(v.x), f2bf(v.y), f2bf(v.z), f2bf(v.w) };
            *(bf16x4*)&As[r][ac4] = s4;
        }
        // stage B transposed: Bs[n][k]  (column loads are wave-coalesced)
#pragma unroll
        for (int i = 0; i < 4; i++) {
            int kk = bgp * 4 + i * 8;
            const float* p = bcol + (size_t)(k0 + kk) * HDIM;
            bf16x4 s4 = { f2bf(p[0]), f2bf(p[HDIM]),
                          f2bf(p[2 * HDIM]), f2bf(p[3 * HDIM]) };
            *(bf16x4*)&Bs[bj][kk] = s4;
        }
        __syncthreads();

        bf16x8 af[4], bfr[4];
#pragma unroll
        for (int i = 0; i < 4; i++) {
            af[i]  = *(const bf16x8*)&As[wm + i * 16 + lr][lq * 8];
            bfr[i] = *(const bf16x8*)&Bs[wn + i * 16 + lr][lq * 8];
        }
#pragma unroll
        for (int mi = 0; mi < 4; mi++)
#pragma unroll
            for (int ni = 0; ni < 4; ni++)
                acc[mi][ni] = __builtin_amdgcn_mfma_f32_16x16x32_bf16(
                    af[mi], bfr[ni], acc[mi][ni], 0, 0, 0);
        __syncthreads();
    }

    // epilogue: bias + fast_gelu, store bf16 h
    const float* b1e = b1 + (size_t)e * HDIM;
#pragma unroll
    for (int mi = 0; mi < 4; mi++) {
#pragma unroll
        for (int r = 0; r < 4; r++) {
            int i = m0 + wm + mi * 16 + lq * 4 + r;
            if (i < ce) {
                __bf16* hrow = hbuf + (size_t)(off + i) * HDIM;
#pragma unroll
                for (int ni = 0; ni < 4; ni++) {
                    int j = n0 + wn + ni * 16 + lr;
                    float v = acc[mi][ni][r] + b1e[j];
                    v = v / (1.0f + __expf(-1.702f * v));   // x*sigmoid(1.702x)
                    hrow[j] = f2bf(v);
                }
            }
        }
    }
}

// ---------------------------------------------------------------------------
// 5. GEMM2: out[tok,:] = gate[tok] * (h·W2[e] + b2[e]) ; scatter by perm
//    BM=64 BN=128 BK=32 (more blocks since N=1024), 4 waves of 32x64
// ---------------------------------------------------------------------------
__global__ __launch_bounds__(256) void gemm2_kernel(
    const __bf16* __restrict__ hbuf, const float* __restrict__ w2,
    const float* __restrict__ b2,
    const int* __restrict__ perm, const int* __restrict__ counts,
    const int* __restrict__ offsets, const float* __restrict__ gatew,
    float* __restrict__ out)
{
    int bx  = blockIdx.x;
    int e   = bx >> 9;            // 64 mt * 8 nt = 512
    int rem = bx & 511;
    int mt  = rem >> 3;
    int nt  = rem & 7;
    int ce  = counts[e];
    int m0  = mt * 64;
    if (m0 >= ce) return;
    int off = offsets[e];
    int n0  = nt * 128;
    const float* B = w2 + (size_t)e * HDIM * DIMK;   // [4096][1024] row-major

    __shared__ __bf16 As[64][40];    // [m][k]
    __shared__ __bf16 Bs[128][40];   // [n][k] transposed

    int t = threadIdx.x;

    // A staging: one 16B chunk per thread: r=t>>2, c8=(t&3)*8 (bf16 source)
    int ar = t >> 2;
    int ac8 = (t & 3) * 8;
    {
        int ri = m0 + ar; if (ri >= ce) ri = ce - 1;
        ar = ar; // keep LDS row
        // store clamped source pointer in register below
    }
    int ri0 = m0 + ar; if (ri0 >= ce) ri0 = ce - 1;
    const __bf16* aptr = hbuf + (size_t)(off + ri0) * HDIM;

    int bj = t & 127;
    int bgp = t >> 7;
    const float* bcol = B + n0 + bj;

    int lane = t & 63;
    int wv   = t >> 6;
    int wm   = (wv >> 1) * 32;
    int wn   = (wv & 1) * 64;
    int lr   = lane & 15;
    int lq   = lane >> 4;

    f32x4 acc[2][4];
#pragma unroll
    for (int mi = 0; mi < 2; mi++)
#pragma unroll
        for (int ni = 0; ni < 4; ni++) acc[mi][ni] = (f32x4)0.0f;

    for (int k0 = 0; k0 < HDIM; k0 += 32) {
        // stage A (already bf16 — straight 16B copy)
        {
            bf16x8 v = *(const bf16x8*)(aptr + k0 + ac8);
            *(bf16x8*)&As[ar][ac8] = v;
        }
        // stage B transposed
#pragma unroll
        for (int i = 0; i < 4; i++) {
            int kk = bgp * 4 + i * 8;
            const float* p = bcol + (size_t)(k0 + kk) * DIMK;
            bf16x4 s4 = { f2bf(p[0]), f2bf(p[DIMK]),
                          f2bf(p[2 * DIMK]), f2bf(p[3 * DIMK]) };
            *(bf16x4*)&Bs[bj][kk] = s4;
        }
        __syncthreads();

        bf16x8 af[2], bfr[4];
#pragma unroll
        for (int i = 0; i < 2; i++)
            af[i] = *(const bf16x8*)&As[wm + i * 16 + lr][lq * 8];
#pragma unroll
        for (int i = 0; i < 4; i++)
            bfr[i] = *(const bf16x8*)&Bs[wn + i * 16 + lr][lq * 8];
#pragma unroll
        for (int mi = 0; mi < 2; mi++)
#pragma unroll
            for (int ni = 0; ni < 4; ni++)
                acc[mi][ni] = __builtin_amdgcn_mfma_f32_16x16x32_bf16(
                    af[mi], bfr[ni], acc[mi][ni], 0, 0, 0);
        __syncthreads();
    }

    // epilogue: bias, gate scale, scatter to out rows
    const float* b2e = b2 + (size_t)e * DIMK;
#pragma unroll
    for (int mi = 0; mi < 2; mi++) {
#pragma unroll
        for (int r = 0; r < 4; r++) {
            int i = m0 + wm + mi * 16 + lq * 4 + r;
            if (i < ce) {
                int tok = perm[off + i];
                float g = gatew[tok];
                float* orow = out + (size_t)tok * DIMK;
#pragma unroll
                for (int ni = 0; ni < 4; ni++) {
                    int j = n0 + wn + ni * 16 + lr;
                    orow[j] = (acc[mi][ni][r] + b2e[j]) * g;
                }
            }
        }
    }
}

// ---------------------------------------------------------------------------
// launch
// ---------------------------------------------------------------------------
extern "C" void kernel_launch(void* const* d_in, const int* in_sizes, int n_in,
                              void* d_out, int out_size, void* d_ws, size_t ws_size,
                              hipStream_t stream)
{
    const float* x  = (const float*)d_in[0];
    const float* wg = (const float*)d_in[1];
    const float* bg = (const float*)d_in[2];
    const float* w1 = (const float*)d_in[3];
    const float* b1 = (const float*)d_in[4];
    const float* w2 = (const float*)d_in[5];
    const float* b2 = (const float*)d_in[6];
    float* out = (float*)d_out;

    char* wsb = (char*)d_ws;
    int*   counts  = (int*)  (wsb + 0);
    int*   cursors = (int*)  (wsb + 32);
    int*   offsets = (int*)  (wsb + 64);
    float* S       = (float*)(wsb + 96);
    float* score   = (float*)(wsb + 128);            // 4096 f32
    int*   texp    = (int*)  (wsb + 16512);          // 4096 i32
    int*   perm    = (int*)  (wsb + 32896);          // 4096 i32
    float* gatew   = (float*)(wsb + 49280);          // 4096 f32
    __bf16* hbuf   = (__bf16*)(wsb + 131072);        // 4096*4096 bf16 = 33.5 MB

    init_kernel<<<1, 64, 0, stream>>>(counts, cursors, S);
    gate_kernel<<<NTOK / 4, 256, 0, stream>>>(x, wg, bg, S, counts, score, texp);
    finalize_kernel<<<1, 64, 0, stream>>>(S, counts, offsets, out + (size_t)NTOK * DIMK);
    assign_kernel<<<NTOK / 256, 256, 0, stream>>>(texp, score, S, offsets,
                                                  cursors, perm, gatew);
    gemm1_kernel<<<NEXP * 32 * 32, 256, 0, stream>>>(x, w1, b1, perm, counts,
                                                     offsets, hbuf);
    gemm2_kernel<<<NEXP * 64 * 8, 256, 0, stream>>>(hbuf, w2, b2, perm, counts,
                                                    offsets, gatew, out);
}

// Round 2
// 603.469 us; speedup vs baseline: 1.0455x; 1.0455x over previous
//
#include <hip/hip_runtime.h>
#include <hip/hip_bf16.h>
#include <math.h>

#define DIMK   1024
#define HDIM   4096
#define NEXP   8
#define NTOK   4096
#define EPSV   1e-6f

typedef __attribute__((ext_vector_type(4))) float  f32x4;
typedef __attribute__((ext_vector_type(8))) __bf16 bf16x8;
typedef __attribute__((ext_vector_type(4))) __bf16 bf16x4;
typedef __attribute__((ext_vector_type(2))) __bf16 bf16x2;

__device__ __forceinline__ __bf16 f2bf(float f) { return (__bf16)f; }

// ---------------------------------------------------------------------------
// 0. init: zero counters
// ---------------------------------------------------------------------------
__global__ void init_kernel(int* counts, int* cursors, float* S) {
    int t = threadIdx.x;
    if (t < NEXP) { counts[t] = 0; cursors[t] = 0; S[t] = 0.0f; }
}

// ---------------------------------------------------------------------------
// 1. gate: one BLOCK per token. float4 loads of x and w_gate.
// ---------------------------------------------------------------------------
__global__ __launch_bounds__(256) void gate_kernel(
    const float* __restrict__ x, const float* __restrict__ wg,
    const float* __restrict__ bg,
    float* S, int* counts, float* score_top, int* texp)
{
    int n = blockIdx.x;
    int t = threadIdx.x;
    f32x4 xv = *(const f32x4*)(x + (size_t)n * DIMK + t * 4);

    float p[NEXP];
#pragma unroll
    for (int e = 0; e < NEXP; e++) p[e] = 0.0f;
#pragma unroll
    for (int j = 0; j < 4; j++) {
        int d = t * 4 + j;
        f32x4 wa = *(const f32x4*)(wg + (size_t)d * NEXP);
        f32x4 wb = *(const f32x4*)(wg + (size_t)d * NEXP + 4);
#pragma unroll
        for (int e = 0; e < 4; e++) { p[e] += xv[j] * wa[e]; p[e + 4] += xv[j] * wb[e]; }
    }
#pragma unroll
    for (int e = 0; e < NEXP; e++) {
#pragma unroll
        for (int off = 32; off > 0; off >>= 1)
            p[e] += __shfl_down(p[e], off, 64);
    }
    __shared__ float red[4][NEXP];
    int lane = t & 63, wv = t >> 6;
    if (lane == 0) {
#pragma unroll
        for (int e = 0; e < NEXP; e++) red[wv][e] = p[e];
    }
    __syncthreads();
    if (t == 0) {
        float l[NEXP]; float m = -1e30f;
#pragma unroll
        for (int e = 0; e < NEXP; e++) {
            l[e] = red[0][e] + red[1][e] + red[2][e] + red[3][e] + bg[e];
            m = fmaxf(m, l[e]);
        }
        float pe[NEXP]; float s = 0.0f;
#pragma unroll
        for (int e = 0; e < NEXP; e++) { pe[e] = __expf(l[e] - m); s += pe[e]; }
        int best = 0; float bv = pe[0];
#pragma unroll
        for (int e = 1; e < NEXP; e++) if (pe[e] > bv) { bv = pe[e]; best = e; }
        float sc = bv / s;
        score_top[n] = sc;
        texp[n] = best;
        atomicAdd(&S[best], sc);
        atomicAdd(&counts[best], 1);
    }
}

// ---------------------------------------------------------------------------
// 2. finalize: offsets scan + aux loss
// ---------------------------------------------------------------------------
__global__ void finalize_kernel(const float* S, const int* counts,
                                int* offsets, float* loss_out)
{
    if (threadIdx.x == 0 && blockIdx.x == 0) {
        int off = 0;
        float loadv[NEXP]; float tot = 0.0f;
        for (int e = 0; e < NEXP; e++) { offsets[e] = off; off += counts[e]; }
        for (int e = 0; e < NEXP; e++) {
            loadv[e] = S[e] / (S[e] + EPSV) * (float)NTOK;
            tot += loadv[e];
        }
        float imp = tot / (float)NTOK;
        float loss = 0.0f;
        for (int e = 0; e < NEXP; e++) { float d = loadv[e] - imp; loss += d * d; }
        loss_out[0] = loss / (float)NEXP;
    }
}

// ---------------------------------------------------------------------------
// 3. assign: compaction permutation + combine weight
// ---------------------------------------------------------------------------
__global__ __launch_bounds__(256) void assign_kernel(
    const int* __restrict__ texp, const float* __restrict__ score_top,
    const float* __restrict__ S, const int* __restrict__ offsets,
    int* cursors, int* perm, float* gatew)
{
    int n = blockIdx.x * 256 + threadIdx.x;
    int e = texp[n];
    int pos = atomicAdd(&cursors[e], 1);
    perm[offsets[e] + pos] = n;
    gatew[n] = score_top[n] / (S[e] + EPSV) * (float)NTOK;
}

// ---------------------------------------------------------------------------
// 3b. bias_init: out[n,:] = b2[e_n,:] * g_n  (also serves as out-zeroing;
//     gemm2 accumulates on top with atomics)
// ---------------------------------------------------------------------------
__global__ __launch_bounds__(256) void bias_init_kernel(
    const int* __restrict__ texp, const float* __restrict__ gatew,
    const float* __restrict__ b2, float* __restrict__ out)
{
    int n = blockIdx.x;
    int t = threadIdx.x;
    int e = texp[n];
    float g = gatew[n];
    f32x4 b = *(const f32x4*)(b2 + (size_t)e * DIMK + t * 4);
    f32x4 o = { b.x * g, b.y * g, b.z * g, b.w * g };
    *(f32x4*)(out + (size_t)n * DIMK + t * 4) = o;
}

// ---------------------------------------------------------------------------
// 4. GEMM1: h = fast_gelu(x[perm]·W1[e] + b1)   BM=128 BN=128 BK=32
//    B staged with float4 loads + in-register transpose (paired-k bf16x2)
// ---------------------------------------------------------------------------
__global__ __launch_bounds__(256) void gemm1_kernel(
    const float* __restrict__ x, const float* __restrict__ w1,
    const float* __restrict__ b1,
    const int* __restrict__ perm, const int* __restrict__ counts,
    const int* __restrict__ offsets, __bf16* __restrict__ hbuf)
{
    int bx  = blockIdx.x;
    int e   = bx >> 10;
    int rem = bx & 1023;
    int mt  = rem >> 5;
    int nt  = rem & 31;
    int ce  = counts[e];
    int m0  = mt * 128;
    if (m0 >= ce) return;
    int off = offsets[e];
    int n0  = nt * 128;
    const float* B = w1 + (size_t)e * DIMK * HDIM;   // [1024][4096]

    __shared__ __bf16 As[128][40];
    __shared__ __bf16 Bs[128][40];

    int t = threadIdx.x;

    // A staging: row r=(t>>3)+32i, float4 chunk (t&7)*4
    const float* aptr[4];
#pragma unroll
    for (int i = 0; i < 4; i++) {
        int r  = (t >> 3) + 32 * i;
        int ri = (m0 + r < ce) ? (m0 + r) : (ce - 1);
        aptr[i] = x + (size_t)perm[off + ri] * DIMK;
    }
    int ac4 = (t & 7) * 4;

    // B staging: n-quad from t>>3, k-pair slot from t&7
    int n4 = ((t >> 3) & 31) * 4;
    int kp = t & 7;
    const float* Bb = B + n0 + n4;

    int lane = t & 63;
    int wv   = t >> 6;
    int wm   = (wv >> 1) * 64;
    int wn   = (wv & 1) * 64;
    int lr   = lane & 15;
    int lq   = lane >> 4;

    f32x4 acc[4][4];
#pragma unroll
    for (int mi = 0; mi < 4; mi++)
#pragma unroll
        for (int ni = 0; ni < 4; ni++) acc[mi][ni] = (f32x4)0.0f;

    for (int k0 = 0; k0 < DIMK; k0 += 32) {
        // A: fp32 -> bf16
#pragma unroll
        for (int i = 0; i < 4; i++) {
            int r = (t >> 3) + 32 * i;
            f32x4 v = *(const f32x4*)(aptr[i] + k0 + ac4);
            bf16x4 s4 = { f2bf(v.x), f2bf(v.y), f2bf(v.z), f2bf(v.w) };
            *(bf16x4*)&As[r][ac4] = s4;
        }
        // B: float4 along n, transpose in registers, paired-k writes
#pragma unroll
        for (int i = 0; i < 2; i++) {
            int p = kp + 8 * i;                      // k-pair 0..15
            const float* p0 = Bb + (size_t)(k0 + 2 * p) * HDIM;
            f32x4 v0 = *(const f32x4*)p0;
            f32x4 v1 = *(const f32x4*)(p0 + HDIM);
#pragma unroll
            for (int j = 0; j < 4; j++) {
                bf16x2 w = { f2bf(v0[j]), f2bf(v1[j]) };
                *(bf16x2*)&Bs[n4 + j][2 * p] = w;
            }
        }
        __syncthreads();

        bf16x8 af[4], bfr[4];
#pragma unroll
        for (int i = 0; i < 4; i++) {
            af[i]  = *(const bf16x8*)&As[wm + i * 16 + lr][lq * 8];
            bfr[i] = *(const bf16x8*)&Bs[wn + i * 16 + lr][lq * 8];
        }
#pragma unroll
        for (int mi = 0; mi < 4; mi++)
#pragma unroll
            for (int ni = 0; ni < 4; ni++)
                acc[mi][ni] = __builtin_amdgcn_mfma_f32_16x16x32_bf16(
                    af[mi], bfr[ni], acc[mi][ni], 0, 0, 0);
        __syncthreads();
    }

    const float* b1e = b1 + (size_t)e * HDIM;
#pragma unroll
    for (int mi = 0; mi < 4; mi++) {
#pragma unroll
        for (int r = 0; r < 4; r++) {
            int i = m0 + wm + mi * 16 + lq * 4 + r;
            if (i < ce) {
                __bf16* hrow = hbuf + (size_t)(off + i) * HDIM;
#pragma unroll
                for (int ni = 0; ni < 4; ni++) {
                    int j = n0 + wn + ni * 16 + lr;
                    float v = acc[mi][ni][r] + b1e[j];
                    v = v / (1.0f + __expf(-1.702f * v));
                    hrow[j] = f2bf(v);
                }
            }
        }
    }
}

// ---------------------------------------------------------------------------
// 5. GEMM2: out[tok,:] += g * (h·W2[e])   BM=64 BN=128 BK=64 split-K=2
// ---------------------------------------------------------------------------
__global__ __launch_bounds__(256) void gemm2_kernel(
    const __bf16* __restrict__ hbuf, const float* __restrict__ w2,
    const int* __restrict__ perm, const int* __restrict__ counts,
    const int* __restrict__ offsets, const float* __restrict__ gatew,
    float* __restrict__ out)
{
    int bx  = blockIdx.x;
    int sk  = bx & 1;             // split-K half
    int rest = bx >> 1;
    int e   = rest >> 9;          // 64 mt * 8 nt
    int rem = rest & 511;
    int mt  = rem >> 3;
    int nt  = rem & 7;
    int ce  = counts[e];
    int m0  = mt * 64;
    if (m0 >= ce) return;
    int off = offsets[e];
    int n0  = nt * 128;
    const float* B = w2 + (size_t)e * HDIM * DIMK;   // [4096][1024]

    __shared__ __bf16 As[64][72];
    __shared__ __bf16 Bs[128][72];

    int t = threadIdx.x;

    // A staging (bf16 source): row r=(t>>3)+32i, chunk (t&7)*8
    const __bf16* aptr[2];
#pragma unroll
    for (int i = 0; i < 2; i++) {
        int r  = (t >> 3) + 32 * i;
        int ri = (m0 + r < ce) ? (m0 + r) : (ce - 1);
        aptr[i] = hbuf + (size_t)(off + ri) * HDIM;
    }
    int ac8 = (t & 7) * 8;

    // B staging map
    int n4 = ((t >> 3) & 31) * 4;
    int kp = t & 7;
    const float* Bb = B + n0 + n4;

    int lane = t & 63;
    int wv   = t >> 6;
    int wm   = (wv >> 1) * 32;
    int wn   = (wv & 1) * 64;
    int lr   = lane & 15;
    int lq   = lane >> 4;

    f32x4 acc[2][4];
#pragma unroll
    for (int mi = 0; mi < 2; mi++)
#pragma unroll
        for (int ni = 0; ni < 4; ni++) acc[mi][ni] = (f32x4)0.0f;

    int kbeg = sk * (HDIM / 2);
    int kend = kbeg + HDIM / 2;
    for (int k0 = kbeg; k0 < kend; k0 += 64) {
        // A: straight bf16x8 copies
#pragma unroll
        for (int i = 0; i < 2; i++) {
            int r = (t >> 3) + 32 * i;
            bf16x8 v = *(const bf16x8*)(aptr[i] + k0 + ac8);
            *(bf16x8*)&As[r][ac8] = v;
        }
        // B: float4 along n + in-register transpose
#pragma unroll
        for (int i = 0; i < 4; i++) {
            int p = kp + 8 * i;                      // k-pair 0..31
            const float* p0 = Bb + (size_t)(k0 + 2 * p) * DIMK;
            f32x4 v0 = *(const f32x4*)p0;
            f32x4 v1 = *(const f32x4*)(p0 + DIMK);
#pragma unroll
            for (int j = 0; j < 4; j++) {
                bf16x2 w = { f2bf(v0[j]), f2bf(v1[j]) };
                *(bf16x2*)&Bs[n4 + j][2 * p] = w;
            }
        }
        __syncthreads();

#pragma unroll
        for (int ks = 0; ks < 2; ks++) {
            bf16x8 af[2], bfr[4];
#pragma unroll
            for (int i = 0; i < 2; i++)
                af[i] = *(const bf16x8*)&As[wm + i * 16 + lr][lq * 8 + ks * 32];
#pragma unroll
            for (int i = 0; i < 4; i++)
                bfr[i] = *(const bf16x8*)&Bs[wn + i * 16 + lr][lq * 8 + ks * 32];
#pragma unroll
            for (int mi = 0; mi < 2; mi++)
#pragma unroll
                for (int ni = 0; ni < 4; ni++)
                    acc[mi][ni] = __builtin_amdgcn_mfma_f32_16x16x32_bf16(
                        af[mi], bfr[ni], acc[mi][ni], 0, 0, 0);
        }
        __syncthreads();
    }

    // epilogue: atomic accumulate g*acc onto out (bias pre-applied)
#pragma unroll
    for (int mi = 0; mi < 2; mi++) {
#pragma unroll
        for (int r = 0; r < 4; r++) {
            int i = m0 + wm + mi * 16 + lq * 4 + r;
            if (i < ce) {
                int tok = perm[off + i];
                float g = gatew[tok];
                float* orow = out + (size_t)tok * DIMK;
#pragma unroll
                for (int ni = 0; ni < 4; ni++) {
                    int j = n0 + wn + ni * 16 + lr;
                    atomicAdd(&orow[j], acc[mi][ni][r] * g);
                }
            }
        }
    }
}

// ---------------------------------------------------------------------------
// launch
// ---------------------------------------------------------------------------
extern "C" void kernel_launch(void* const* d_in, const int* in_sizes, int n_in,
                              void* d_out, int out_size, void* d_ws, size_t ws_size,
                              hipStream_t stream)
{
    const float* x  = (const float*)d_in[0];
    const float* wg = (const float*)d_in[1];
    const float* bg = (const float*)d_in[2];
    const float* w1 = (const float*)d_in[3];
    const float* b1 = (const float*)d_in[4];
    const float* w2 = (const float*)d_in[5];
    const float* b2 = (const float*)d_in[6];
    float* out = (float*)d_out;

    char* wsb = (char*)d_ws;
    int*   counts  = (int*)  (wsb + 0);
    int*   cursors = (int*)  (wsb + 32);
    int*   offsets = (int*)  (wsb + 64);
    float* S       = (float*)(wsb + 96);
    float* score   = (float*)(wsb + 128);
    int*   texp    = (int*)  (wsb + 16512);
    int*   perm    = (int*)  (wsb + 32896);
    float* gatew   = (float*)(wsb + 49280);
    __bf16* hbuf   = (__bf16*)(wsb + 131072);        // 33.5 MB

    init_kernel<<<1, 64, 0, stream>>>(counts, cursors, S);
    gate_kernel<<<NTOK, 256, 0, stream>>>(x, wg, bg, S, counts, score, texp);
    finalize_kernel<<<1, 64, 0, stream>>>(S, counts, offsets, out + (size_t)NTOK * DIMK);
    assign_kernel<<<NTOK / 256, 256, 0, stream>>>(texp, score, S, offsets,
                                                  cursors, perm, gatew);
    bias_init_kernel<<<NTOK, 256, 0, stream>>>(texp, gatew, b2, out);
    gemm1_kernel<<<NEXP * 32 * 32, 256, 0, stream>>>(x, w1, b1, perm, counts,
                                                     offsets, hbuf);
    gemm2_kernel<<<NEXP * 64 * 8 * 2, 256, 0, stream>>>(hbuf, w2, perm, counts,
                                                        offsets, gatew, out);
}

// Round 3
// 578.752 us; speedup vs baseline: 1.0901x; 1.0427x over previous
//
#include <hip/hip_runtime.h>
#include <hip/hip_bf16.h>
#include <math.h>

#define DIMK   1024
#define HDIM   4096
#define NEXP   8
#define NTOK   4096
#define EPSV   1e-6f

typedef __attribute__((ext_vector_type(4))) float  f32x4;
typedef __attribute__((ext_vector_type(8))) __bf16 bf16x8;
typedef __attribute__((ext_vector_type(4))) __bf16 bf16x4;

__device__ __forceinline__ __bf16 f2bf(float f) { return (__bf16)f; }

__device__ __forceinline__ void gload_lds16(const void* g, void* l) {
    __builtin_amdgcn_global_load_lds(
        (const __attribute__((address_space(1))) void*)g,
        (__attribute__((address_space(3))) void*)l, 16, 0, 0);
}

// ---------------------------------------------------------------------------
// 0. init
// ---------------------------------------------------------------------------
__global__ void init_kernel(int* counts, int* cursors, float* S) {
    int t = threadIdx.x;
    if (t < NEXP) { counts[t] = 0; cursors[t] = 0; S[t] = 0.0f; }
}

// ---------------------------------------------------------------------------
// 1. gate
// ---------------------------------------------------------------------------
__global__ __launch_bounds__(256) void gate_kernel(
    const float* __restrict__ x, const float* __restrict__ wg,
    const float* __restrict__ bg,
    float* S, int* counts, float* score_top, int* texp)
{
    int n = blockIdx.x;
    int t = threadIdx.x;
    f32x4 xv = *(const f32x4*)(x + (size_t)n * DIMK + t * 4);

    float p[NEXP];
#pragma unroll
    for (int e = 0; e < NEXP; e++) p[e] = 0.0f;
#pragma unroll
    for (int j = 0; j < 4; j++) {
        int d = t * 4 + j;
        f32x4 wa = *(const f32x4*)(wg + (size_t)d * NEXP);
        f32x4 wb = *(const f32x4*)(wg + (size_t)d * NEXP + 4);
#pragma unroll
        for (int e = 0; e < 4; e++) { p[e] += xv[j] * wa[e]; p[e + 4] += xv[j] * wb[e]; }
    }
#pragma unroll
    for (int e = 0; e < NEXP; e++) {
#pragma unroll
        for (int off = 32; off > 0; off >>= 1)
            p[e] += __shfl_down(p[e], off, 64);
    }
    __shared__ float red[4][NEXP];
    int lane = t & 63, wv = t >> 6;
    if (lane == 0) {
#pragma unroll
        for (int e = 0; e < NEXP; e++) red[wv][e] = p[e];
    }
    __syncthreads();
    if (t == 0) {
        float l[NEXP]; float m = -1e30f;
#pragma unroll
        for (int e = 0; e < NEXP; e++) {
            l[e] = red[0][e] + red[1][e] + red[2][e] + red[3][e] + bg[e];
            m = fmaxf(m, l[e]);
        }
        float pe[NEXP]; float s = 0.0f;
#pragma unroll
        for (int e = 0; e < NEXP; e++) { pe[e] = __expf(l[e] - m); s += pe[e]; }
        int best = 0; float bv = pe[0];
#pragma unroll
        for (int e = 1; e < NEXP; e++) if (pe[e] > bv) { bv = pe[e]; best = e; }
        float sc = bv / s;
        score_top[n] = sc;
        texp[n] = best;
        atomicAdd(&S[best], sc);
        atomicAdd(&counts[best], 1);
    }
}

// ---------------------------------------------------------------------------
// 2. finalize
// ---------------------------------------------------------------------------
__global__ void finalize_kernel(const float* S, const int* counts,
                                int* offsets, float* loss_out)
{
    if (threadIdx.x == 0 && blockIdx.x == 0) {
        int off = 0;
        float loadv[NEXP]; float tot = 0.0f;
        for (int e = 0; e < NEXP; e++) { offsets[e] = off; off += counts[e]; }
        for (int e = 0; e < NEXP; e++) {
            loadv[e] = S[e] / (S[e] + EPSV) * (float)NTOK;
            tot += loadv[e];
        }
        float imp = tot / (float)NTOK;
        float loss = 0.0f;
        for (int e = 0; e < NEXP; e++) { float d = loadv[e] - imp; loss += d * d; }
        loss_out[0] = loss / (float)NEXP;
    }
}

// ---------------------------------------------------------------------------
// 3. assign
// ---------------------------------------------------------------------------
__global__ __launch_bounds__(256) void assign_kernel(
    const int* __restrict__ texp, const float* __restrict__ score_top,
    const float* __restrict__ S, const int* __restrict__ offsets,
    int* cursors, int* perm, float* gatew)
{
    int n = blockIdx.x * 256 + threadIdx.x;
    int e = texp[n];
    int pos = atomicAdd(&cursors[e], 1);
    perm[offsets[e] + pos] = n;
    gatew[n] = score_top[n] / (S[e] + EPSV) * (float)NTOK;
}

// ---------------------------------------------------------------------------
// 3b. bias_init: out[n,:] = b2[e_n,:]*g_n (gemm2 atomically accumulates)
// ---------------------------------------------------------------------------
__global__ __launch_bounds__(256) void bias_init_kernel(
    const int* __restrict__ texp, const float* __restrict__ gatew,
    const float* __restrict__ b2, float* __restrict__ out)
{
    int n = blockIdx.x;
    int t = threadIdx.x;
    int e = texp[n];
    float g = gatew[n];
    f32x4 b = *(const f32x4*)(b2 + (size_t)e * DIMK + t * 4);
    f32x4 o = { b.x * g, b.y * g, b.z * g, b.w * g };
    *(f32x4*)(out + (size_t)n * DIMK + t * 4) = o;
}

// ---------------------------------------------------------------------------
// P1. convert x -> bf16 (same layout)
// ---------------------------------------------------------------------------
__global__ __launch_bounds__(256) void cvt_kernel(
    const float* __restrict__ x, __bf16* __restrict__ xb)
{
    size_t i = ((size_t)blockIdx.x * 256 + threadIdx.x) * 8;
    f32x4 a = *(const f32x4*)(x + i);
    f32x4 b = *(const f32x4*)(x + i + 4);
    bf16x8 w = { f2bf(a.x), f2bf(a.y), f2bf(a.z), f2bf(a.w),
                 f2bf(b.x), f2bf(b.y), f2bf(b.z), f2bf(b.w) };
    *(bf16x8*)(xb + i) = w;
}

// ---------------------------------------------------------------------------
// P2. transpose+convert: src[e][K][N] f32 -> dst[e][N][K] bf16, 64x64 tiles
// ---------------------------------------------------------------------------
__global__ __launch_bounds__(256) void transpose_kernel(
    const float* __restrict__ src, __bf16* __restrict__ dst, int K, int N)
{
    int tilesN = N >> 6;
    int per = (K >> 6) * tilesN;
    int e = blockIdx.x / per; int r = blockIdx.x % per;
    int tk = r / tilesN, tn = r % tilesN;
    const float* S = src + (size_t)e * K * N + (size_t)(tk << 6) * N + (tn << 6);
    __bf16* D = dst + (size_t)e * K * N + (size_t)(tn << 6) * K + (tk << 6);
    __shared__ __bf16 T[64 * 68];
    int t = threadIdx.x;
#pragma unroll
    for (int i = 0; i < 4; i++) {
        int ch = t + 256 * i;
        int k = ch >> 4, n4 = (ch & 15) << 2;
        f32x4 v = *(const f32x4*)(S + (size_t)k * N + n4);
#pragma unroll
        for (int j = 0; j < 4; j++) T[(n4 + j) * 68 + k] = f2bf(v[j]);
    }
    __syncthreads();
#pragma unroll
    for (int i = 0; i < 2; i++) {
        int o = t + 256 * i;
        int n = o >> 3, kc = o & 7;
        bf16x4 a = *(const bf16x4*)&T[n * 68 + kc * 8];
        bf16x4 b = *(const bf16x4*)&T[n * 68 + kc * 8 + 4];
        bf16x8 w = { a.x, a.y, a.z, a.w, b.x, b.y, b.z, b.w };
        *(bf16x8*)(D + (size_t)n * K + kc * 8) = w;
    }
}

// ---------------------------------------------------------------------------
// 4. GEMM1: h = gelu(xbf[perm]·w1t^T + b1). BM=BN=128 BK=64, m97 structure.
//    LDS unpadded, 16B chunks XOR-swizzled by (row&7): staging via
//    global_load_lds dwordx4; fragments via ds_read_b128 (2-way, free).
// ---------------------------------------------------------------------------
__global__ __launch_bounds__(256) void gemm1_kernel(
    const __bf16* __restrict__ xbf, const __bf16* __restrict__ w1t,
    const float* __restrict__ b1,
    const int* __restrict__ perm, const int* __restrict__ counts,
    const int* __restrict__ offsets, __bf16* __restrict__ hbuf)
{
    int bx  = blockIdx.x;
    int e   = bx >> 10;
    int rem = bx & 1023;
    int mt  = rem >> 5, nt = rem & 31;
    int ce  = counts[e];
    int m0  = mt * 128;
    if (m0 >= ce) return;
    int off = offsets[e];
    int n0  = nt * 128;
    const __bf16* Bsrc = w1t + (size_t)e * DIMK * HDIM + (size_t)n0 * DIMK;

    __shared__ __bf16 As[128 * 64];
    __shared__ __bf16 Bs[128 * 64];

    int t = threadIdx.x;
    int lane = t & 63, wv = t >> 6;
    int wm = (wv >> 1) * 64, wn = (wv & 1) * 64;
    int lr = lane & 15, lq = lane >> 4;

    const __bf16* ag[4]; const __bf16* bg[4];
    __bf16 *al[4], *bl[4];
#pragma unroll
    for (int c = 0; c < 4; c++) {
        int s = c * 256 + t;
        int row = s >> 3, pc = s & 7;
        int gc = pc ^ (row & 7);
        int ri = m0 + row; if (ri >= ce) ri = ce - 1;
        ag[c] = xbf + (size_t)perm[off + ri] * DIMK + gc * 8;
        bg[c] = Bsrc + (size_t)row * DIMK + gc * 8;
        al[c] = As + s * 8;
        bl[c] = Bs + s * 8;
    }

    f32x4 acc[4][4];
#pragma unroll
    for (int mi = 0; mi < 4; mi++)
#pragma unroll
        for (int ni = 0; ni < 4; ni++) acc[mi][ni] = (f32x4)0.0f;

    for (int k0 = 0; k0 < DIMK; k0 += 64) {
#pragma unroll
        for (int c = 0; c < 4; c++) gload_lds16(ag[c], al[c]);
#pragma unroll
        for (int c = 0; c < 4; c++) gload_lds16(bg[c], bl[c]);
        __syncthreads();
#pragma unroll
        for (int ks = 0; ks < 2; ks++) {
            bf16x8 af[4], bfr[4];
#pragma unroll
            for (int i = 0; i < 4; i++) {
                int ra = wm + i * 16 + lr;
                af[i]  = *(const bf16x8*)(As + ra * 64 + (((ks * 4 + lq) ^ (ra & 7)) << 3));
                int rb = wn + i * 16 + lr;
                bfr[i] = *(const bf16x8*)(Bs + rb * 64 + (((ks * 4 + lq) ^ (rb & 7)) << 3));
            }
#pragma unroll
            for (int mi = 0; mi < 4; mi++)
#pragma unroll
                for (int ni = 0; ni < 4; ni++)
                    acc[mi][ni] = __builtin_amdgcn_mfma_f32_16x16x32_bf16(
                        af[mi], bfr[ni], acc[mi][ni], 0, 0, 0);
        }
        __syncthreads();
#pragma unroll
        for (int c = 0; c < 4; c++) { ag[c] += 64; bg[c] += 64; }
    }

    const float* b1e = b1 + (size_t)e * HDIM;
#pragma unroll
    for (int mi = 0; mi < 4; mi++) {
#pragma unroll
        for (int rr = 0; rr < 4; rr++) {
            int i = m0 + wm + mi * 16 + lq * 4 + rr;
            if (i < ce) {
                __bf16* hrow = hbuf + (size_t)(off + i) * HDIM;
#pragma unroll
                for (int ni = 0; ni < 4; ni++) {
                    int j = n0 + wn + ni * 16 + lr;
                    float v = acc[mi][ni][rr] + b1e[j];
                    v = v / (1.0f + __expf(-1.702f * v));
                    hrow[j] = f2bf(v);
                }
            }
        }
    }
}

// ---------------------------------------------------------------------------
// 5. GEMM2: out[tok,:] += g*(h·w2t^T). BM=BN=128 BK=64 split-K=2, atomics.
// ---------------------------------------------------------------------------
__global__ __launch_bounds__(256) void gemm2_kernel(
    const __bf16* __restrict__ hbuf, const __bf16* __restrict__ w2t,
    const int* __restrict__ perm, const int* __restrict__ counts,
    const int* __restrict__ offsets, const float* __restrict__ gatew,
    float* __restrict__ out)
{
    int bx = blockIdx.x;
    int sk = bx & 1; int r = bx >> 1;
    int e = r >> 8; int rem = r & 255;
    int mt = rem >> 3, nt = rem & 7;
    int ce = counts[e];
    int m0 = mt * 128;
    if (m0 >= ce) return;
    int off = offsets[e];
    int n0 = nt * 128;
    int kbeg = sk * (HDIM / 2);
    const __bf16* Bsrc = w2t + (size_t)e * HDIM * DIMK + (size_t)n0 * HDIM;

    __shared__ __bf16 As[128 * 64];
    __shared__ __bf16 Bs[128 * 64];

    int t = threadIdx.x;
    int lane = t & 63, wv = t >> 6;
    int wm = (wv >> 1) * 64, wn = (wv & 1) * 64;
    int lr = lane & 15, lq = lane >> 4;

    const __bf16* ag[4]; const __bf16* bg[4];
    __bf16 *al[4], *bl[4];
#pragma unroll
    for (int c = 0; c < 4; c++) {
        int s = c * 256 + t;
        int row = s >> 3, pc = s & 7;
        int gc = pc ^ (row & 7);
        int ri = m0 + row; if (ri >= ce) ri = ce - 1;
        ag[c] = hbuf + (size_t)(off + ri) * HDIM + kbeg + gc * 8;
        bg[c] = Bsrc + (size_t)row * HDIM + kbeg + gc * 8;
        al[c] = As + s * 8;
        bl[c] = Bs + s * 8;
    }

    f32x4 acc[4][4];
#pragma unroll
    for (int mi = 0; mi < 4; mi++)
#pragma unroll
        for (int ni = 0; ni < 4; ni++) acc[mi][ni] = (f32x4)0.0f;

    for (int k0 = 0; k0 < HDIM / 2; k0 += 64) {
#pragma unroll
        for (int c = 0; c < 4; c++) gload_lds16(ag[c], al[c]);
#pragma unroll
        for (int c = 0; c < 4; c++) gload_lds16(bg[c], bl[c]);
        __syncthreads();
#pragma unroll
        for (int ks = 0; ks < 2; ks++) {
            bf16x8 af[4], bfr[4];
#pragma unroll
            for (int i = 0; i < 4; i++) {
                int ra = wm + i * 16 + lr;
                af[i]  = *(const bf16x8*)(As + ra * 64 + (((ks * 4 + lq) ^ (ra & 7)) << 3));
                int rb = wn + i * 16 + lr;
                bfr[i] = *(const bf16x8*)(Bs + rb * 64 + (((ks * 4 + lq) ^ (rb & 7)) << 3));
            }
#pragma unroll
            for (int mi = 0; mi < 4; mi++)
#pragma unroll
                for (int ni = 0; ni < 4; ni++)
                    acc[mi][ni] = __builtin_amdgcn_mfma_f32_16x16x32_bf16(
                        af[mi], bfr[ni], acc[mi][ni], 0, 0, 0);
        }
        __syncthreads();
#pragma unroll
        for (int c = 0; c < 4; c++) { ag[c] += 64; bg[c] += 64; }
    }

#pragma unroll
    for (int mi = 0; mi < 4; mi++) {
#pragma unroll
        for (int rr = 0; rr < 4; rr++) {
            int i = m0 + wm + mi * 16 + lq * 4 + rr;
            if (i < ce) {
                int tok = perm[off + i];
                float g = gatew[tok];
                float* orow = out + (size_t)tok * DIMK;
#pragma unroll
                for (int ni = 0; ni < 4; ni++) {
                    int j = n0 + wn + ni * 16 + lr;
                    atomicAdd(&orow[j], acc[mi][ni][rr] * g);
                }
            }
        }
    }
}

// ---------------------------------------------------------------------------
// launch
// ---------------------------------------------------------------------------
extern "C" void kernel_launch(void* const* d_in, const int* in_sizes, int n_in,
                              void* d_out, int out_size, void* d_ws, size_t ws_size,
                              hipStream_t stream)
{
    const float* x  = (const float*)d_in[0];
    const float* wg = (const float*)d_in[1];
    const float* bg = (const float*)d_in[2];
    const float* w1 = (const float*)d_in[3];
    const float* b1 = (const float*)d_in[4];
    const float* w2 = (const float*)d_in[5];
    const float* b2 = (const float*)d_in[6];
    float* out = (float*)d_out;

    char* wsb = (char*)d_ws;
    int*   counts  = (int*)  (wsb + 0);
    int*   cursors = (int*)  (wsb + 32);
    int*   offsets = (int*)  (wsb + 64);
    float* S       = (float*)(wsb + 96);
    float* score   = (float*)(wsb + 128);
    int*   texp    = (int*)  (wsb + 16512);
    int*   perm    = (int*)  (wsb + 32896);
    float* gatew   = (float*)(wsb + 49280);
    __bf16* hbuf   = (__bf16*)(wsb + 131072);      // 33,554,432 B
    __bf16* xbf    = (__bf16*)(wsb + 33685504);    //  8,388,608 B
    __bf16* w1t    = (__bf16*)(wsb + 42074112);    // 67,108,864 B
    __bf16* w2t    = (__bf16*)(wsb + 109182976);   // 67,108,864 B  (end ~168 MB)

    init_kernel<<<1, 64, 0, stream>>>(counts, cursors, S);
    gate_kernel<<<NTOK, 256, 0, stream>>>(x, wg, bg, S, counts, score, texp);
    finalize_kernel<<<1, 64, 0, stream>>>(S, counts, offsets, out + (size_t)NTOK * DIMK);
    assign_kernel<<<NTOK / 256, 256, 0, stream>>>(texp, score, S, offsets,
                                                  cursors, perm, gatew);
    bias_init_kernel<<<NTOK, 256, 0, stream>>>(texp, gatew, b2, out);
    cvt_kernel<<<(NTOK * DIMK) / (256 * 8), 256, 0, stream>>>(x, xbf);
    transpose_kernel<<<NEXP * 16 * 64, 256, 0, stream>>>(w1, w1t, DIMK, HDIM);
    transpose_kernel<<<NEXP * 64 * 16, 256, 0, stream>>>(w2, w2t, HDIM, DIMK);
    gemm1_kernel<<<NEXP * 32 * 32, 256, 0, stream>>>(xbf, w1t, b1, perm, counts,
                                                     offsets, hbuf);
    gemm2_kernel<<<NEXP * 32 * 8 * 2, 256, 0, stream>>>(hbuf, w2t, perm, counts,
                                                        offsets, gatew, out);
}